// Round 8
// baseline (203.722 us; speedup 1.0000x reference)
//
#include <hip/hip_runtime.h>

typedef unsigned short u16;
typedef unsigned long long u64;
typedef __bf16 bf16x8 __attribute__((ext_vector_type(8)));
typedef float f32x4 __attribute__((ext_vector_type(4)));

__device__ __forceinline__ u16 f2b(float f) {
    unsigned int u = __float_as_uint(f);
    u += 0x7fffu + ((u >> 16) & 1u);   // RNE
    return (u16)(u >> 16);
}

// async global->LDS, 16B per lane; LDS dest is wave-uniform base + lane*16B.
__device__ __forceinline__ void ld_lds16(const u16* g, u16* l) {
    __builtin_amdgcn_global_load_lds(
        (__attribute__((address_space(1))) void*)(uintptr_t)(const void*)g,
        (__attribute__((address_space(3))) void*)l, 16, 0, 0);
}

// ---------------------------------------------------------------------------
// Fused prologue: three independent jobs in one dispatch (block-role switch).
//   blocks [0,832):      weight pack f32->bf16
//   blocks [832,1344):   knn phase-1 (per-slab best, NO atomics)
//   blocks [1344,3392):  transpose emb1->emb1t, emb2->emb2t (f32 -> bf16)
// ---------------------------------------------------------------------------
#define PREP_PACK_END  832
#define PREP_KNN_END   1344   // 64 ref-slabs x 8 query-blocks
#define PREP_TRANS_END 3392   // 128 n-tiles x 8 f-tiles x 2 sources

__global__ __launch_bounds__(256) void prep_k(
    const float* __restrict__ w1r, const float* __restrict__ w1t,
    const float* __restrict__ w2r, const float* __restrict__ w2t,
    const float* __restrict__ w3r, const float* __restrict__ w3t,
    u16* __restrict__ wdst,
    const float* __restrict__ t1, const float* __restrict__ t2,
    u64* __restrict__ part,
    const float* __restrict__ e1, const float* __restrict__ e2,
    u16* __restrict__ o1, u16* __restrict__ o2)
{
    __shared__ __align__(16) float smem[64 * 65];
    const int bid = blockIdx.x;
    const int t = threadIdx.x;

    if (bid < PREP_PACK_END) {
        // ---- weight pack: [w1r|w1t|w2r|w2t|w3r|w3t] -> bf16 ----
        size_t i = (size_t)bid * 2048 + (size_t)t * 8;
        const float* src; size_t off;
        if (i < 655360)       { src = w1r; off = 0; }
        else if (i < 1310720) { src = w1t; off = 655360; }
        else if (i < 1474560) { src = w2r; off = 1310720; }
        else if (i < 1638400) { src = w2t; off = 1474560; }
        else if (i < 1671168) { src = w3r; off = 1638400; }
        else                  { src = w3t; off = 1671168; }
        const float4 lo = *(const float4*)(src + (i - off));
        const float4 hi = *(const float4*)(src + (i - off) + 4);
        ushort4 o0v, o1v;
        o0v.x = f2b(lo.x); o0v.y = f2b(lo.y); o0v.z = f2b(lo.z); o0v.w = f2b(lo.w);
        o1v.x = f2b(hi.x); o1v.y = f2b(hi.y); o1v.z = f2b(hi.z); o1v.w = f2b(hi.w);
        *(ushort4*)(wdst + i) = o0v;
        *(ushort4*)(wdst + i + 4) = o1v;
    } else if (bid < PREP_KNN_END) {
        // ---- knn phase-1: slab rs (128 refs), query-block qb (1024 queries) ----
        float4* ref = (float4*)smem;
        const int rb = bid - PREP_PACK_END;
        const int rs = rb & 63;
        const int qb = rb >> 6;
        if (t < 128) {
            int i = rs * 128 + t;
            float x = t1[i], y = t1[8192 + i], z = t1[16384 + i];
            float rr = __fadd_rn(__fadd_rn(__fmul_rn(x, x), __fmul_rn(y, y)), __fmul_rn(z, z));
            ref[t] = make_float4(x, y, z, rr);
        }
        __syncthreads();

        float qx[4], qy[4], qz[4], qq[4], bestd[4];
        int besti[4];
        const int q0 = qb * 1024 + t;
#pragma unroll
        for (int j = 0; j < 4; ++j) {
            int q = q0 + j * 256;
            qx[j] = t2[q]; qy[j] = t2[8192 + q]; qz[j] = t2[16384 + q];
            qq[j] = __fadd_rn(__fadd_rn(__fmul_rn(qx[j], qx[j]), __fmul_rn(qy[j], qy[j])),
                              __fmul_rn(qz[j], qz[j]));
            bestd[j] = __uint_as_float(0x7f800000u);
            besti[j] = 0;
        }
        for (int i = 0; i < 128; ++i) {
            float4 r = ref[i];
#pragma unroll
            for (int j = 0; j < 4; ++j) {
                float g = __fmaf_rn(qz[j], r.z, __fmaf_rn(qy[j], r.y, __fmul_rn(qx[j], r.x)));
                float d2 = __fsub_rn(__fadd_rn(r.w, qq[j]), __fmul_rn(2.0f, g));
                if (d2 < bestd[j]) { bestd[j] = d2; besti[j] = i + rs * 128; }
            }
        }
#pragma unroll
        for (int j = 0; j < 4; ++j) {
            u64 key = ((u64)__float_as_uint(bestd[j]) << 32) | (unsigned int)besti[j];
            part[(size_t)rs * 8192 + q0 + j * 256] = key;
        }
    } else {
        // ---- transpose: z=0 emb1->emb1t, z=1 emb2->emb2t (both stride 512) ----
        float (*tile)[65] = (float(*)[65])smem;
        const int tb = bid - PREP_KNN_END;
        const int z = tb >> 10;
        const int rem = tb & 1023;
        const int fy = rem >> 7;      // 8 f-tiles
        const int nx = rem & 127;     // 128 n-tiles
        const float* in = z ? e2 : e1;
        u16* out = z ? o2 : o1;
        const int n0 = nx * 64, f0 = fy * 64;
        const int c = t & 63, r4 = t >> 6;
#pragma unroll
        for (int p = 0; p < 16; ++p) {
            int fr = p * 4 + r4;
            tile[fr][c] = in[(size_t)(f0 + fr) * 8192 + n0 + c];
        }
        __syncthreads();
        const int fc = (t & 15) * 4;    // f-chunk of 4
        const int nr4 = t >> 4;         // 16 n-rows covered per pass
#pragma unroll
        for (int p = 0; p < 4; ++p) {
            int nr = p * 16 + nr4;
            ushort4 o;
            o.x = f2b(tile[fc + 0][nr]); o.y = f2b(tile[fc + 1][nr]);
            o.z = f2b(tile[fc + 2][nr]); o.w = f2b(tile[fc + 3][nr]);
            *(ushort4*)&out[(size_t)(n0 + nr) * 512 + f0 + fc] = o;
        }
    }
}

// ---------------------------------------------------------------------------
// Layer 1 GEMM, TN=128 / BK=32, DEPTH-2 PIPELINE with counted vmcnt (T3+T4):
// 4 LDS buffers; per iter: issue loads for tile k+2, s_waitcnt vmcnt(8)
// (waits ONLY tile k's loads -> 8 stay in flight across the barrier), raw
// s_barrier, ds_read+MFMA tile k. Never vmcnt(0) in the main loop: the
// gathered-B HBM latency (~900cy) is covered by ~2 iterations.
// WAR safety: stage at iter k targets the buffer read at k-2, separated by
// the k-1 barrier; waves are <=1 barrier apart (4 bufs needed, not 3).
// Fused: in-block knn slab-reduce + gather:
//   B row n: k<512 -> emb1t[idx[n]][k] ; k>=512 -> emb2t[n][k-512]
// ---------------------------------------------------------------------------
__global__ __launch_bounds__(256) void gemm1_k(
    const u16* __restrict__ Ar, const u16* __restrict__ At,
    const float* __restrict__ biasr, const float* __restrict__ biast,
    const u16* __restrict__ emb1t, const u16* __restrict__ emb2t,
    const u64* __restrict__ part,
    u16* __restrict__ Ct)                    // h1t, stride 1280
{
    constexpr int K = 1024;
    constexpr int NT = K / 32;               // 32 K-tiles
    __shared__ __align__(16) u16 lds_a[4][4096];   // 128 x 32 per buf
    __shared__ __align__(16) u16 lds_b[4][4096];
    __shared__ u64 red[2][128];
    __shared__ unsigned int idx_l[128];

    const int t = threadIdx.x;
    const int n0 = blockIdx.x * 128;
    const int m0 = blockIdx.y * 128;
    const int branch = blockIdx.z;

    const u16* A = branch ? At : Ar;
    const float* bias = branch ? biast : biasr;
    const int out_off = branch * 640;

    const int w = t >> 6, l = t & 63;
    const int sr = l >> 2, sc = (l & 3) * 8;

    // ---- in-block knn reduce: idx for rows [n0, n0+128) ----
    {
        const int rrow = t & 127, rhalf = t >> 7;   // 2 threads/row, 32 slabs each
        const u64* pp = part + (size_t)rhalf * 32 * 8192 + (n0 + rrow);
        u64 best = ~0ull;
#pragma unroll 8
        for (int s = 0; s < 32; ++s) {
            u64 k = pp[(size_t)s * 8192];
            best = k < best ? k : best;
        }
        red[rhalf][rrow] = best;
    }
    __syncthreads();
    if (t < 128) {
        u64 a = red[0][t], b = red[1][t];
        idx_l[t] = (unsigned int)(a < b ? a : b);
    }
    __syncthreads();

    const u16* Abase = A + (size_t)(m0 + w * 32 + sr) * K + sc;      // +16*K for half 1
    const int row0 = n0 + w * 32 + sr;
    const int row1 = row0 + 16;
    const u16* b0e1 = emb1t + (size_t)idx_l[w * 32 + sr] * 512 + sc;
    const u16* b1e1 = emb1t + (size_t)idx_l[w * 32 + sr + 16] * 512 + sc;
    const u16* b0e2 = emb2t + (size_t)row0 * 512 + sc;
    const u16* b1e2 = emb2t + (size_t)row1 * 512 + sc;

    const int wm = (w & 1) * 64;
    const int wn = (w >> 1) * 64;
    const int lrow = l & 15, quad = l >> 4;

    // stage tile (4 loads/wave): wave-uniform branch on tile_kt
    auto STAGE = [&](int tile_kt, int buf) {
        u16* la = &lds_a[buf][w * 1024];
        u16* lb = &lds_b[buf][w * 1024];
        ld_lds16(Abase + tile_kt,            la);
        ld_lds16(Abase + 16 * K + tile_kt,   la + 512);
        if (tile_kt < 512) {
            ld_lds16(b0e1 + tile_kt,         lb);
            ld_lds16(b1e1 + tile_kt,         lb + 512);
        } else {
            ld_lds16(b0e2 + (tile_kt - 512), lb);
            ld_lds16(b1e2 + (tile_kt - 512), lb + 512);
        }
    };

    f32x4 acc[4][4];
#pragma unroll
    for (int i = 0; i < 4; ++i)
#pragma unroll
        for (int j = 0; j < 4; ++j)
            acc[i][j] = (f32x4){0.f, 0.f, 0.f, 0.f};

    // prologue: 2 tiles in flight
    STAGE(0, 0);
    STAGE(32, 1);

    for (int it = 0; it < NT; ++it) {
        const int buf = it & 3;
        if (it + 2 < NT) {
            STAGE((it + 2) * 32, (it + 2) & 3);
            asm volatile("s_waitcnt vmcnt(8)" ::: "memory");   // tile it done; 8 in flight
        } else if (it + 1 < NT) {
            asm volatile("s_waitcnt vmcnt(4)" ::: "memory");   // tile it done; 4 in flight
        } else {
            asm volatile("s_waitcnt vmcnt(0)" ::: "memory");   // last tile
        }
        __builtin_amdgcn_s_barrier();

        const u16* fa = &lds_a[buf][(wm + lrow) * 32 + quad * 8];
        const u16* fb = &lds_b[buf][(wn + lrow) * 32 + quad * 8];
        bf16x8 af[4], bfr[4];
#pragma unroll
        for (int i = 0; i < 4; ++i) {
            af[i]  = *(const bf16x8*)(fa + i * 512);
            bfr[i] = *(const bf16x8*)(fb + i * 512);
        }
#pragma unroll
        for (int i = 0; i < 4; ++i)
#pragma unroll
            for (int j = 0; j < 4; ++j)
                acc[i][j] = __builtin_amdgcn_mfma_f32_16x16x32_bf16(
                    af[i], bfr[j], acc[i][j], 0, 0, 0);
    }

    // epilogue: D row m = quad*4+reg, col n = lrow; relu always
#pragma unroll
    for (int i = 0; i < 4; ++i) {
        const int mbase = m0 + wm + i * 16 + quad * 4;
        const float4 bbv = *(const float4*)&bias[mbase];
#pragma unroll
        for (int j = 0; j < 4; ++j) {
            const int n = n0 + wn + j * 16 + lrow;
            f32x4 v = acc[i][j];
            float x0 = fmaxf(v[0] + bbv.x, 0.f);
            float x1 = fmaxf(v[1] + bbv.y, 0.f);
            float x2 = fmaxf(v[2] + bbv.z, 0.f);
            float x3 = fmaxf(v[3] + bbv.w, 0.f);
            ushort4 o;
            o.x = f2b(x0); o.y = f2b(x1); o.z = f2b(x2); o.w = f2b(x3);
            *(ushort4*)&Ct[(size_t)n * 1280 + out_off + mbase] = o;
        }
    }
}

// ---------------------------------------------------------------------------
// Fused layers 2+3+4: one block per 32-row n-tile (grid 256 = 1 block/CU).
// Dependency is block-local: h3 rows [n0,n0+32) need only h2 of those rows,
// which need only h1 rows [n0,n0+32). Per branch (sequential):
//   phase 2: h2[32][256] = relu(w2 . h1seg + b2)  -> LDS panels (bf16)
//   phase 3: h3[32][128] = relu(w3 . h2 + b3)     -> LDS f32 (overlays A-buf)
//   final  : obj-selected w4 rows (NR=4/3) dot h3 -> out
// ---------------------------------------------------------------------------
__global__ __launch_bounds__(256) void gemm23_k(
    const u16* __restrict__ w2rp, const u16* __restrict__ w2tp,
    const float* __restrict__ b2r, const float* __restrict__ b2t,
    const u16* __restrict__ w3rp, const u16* __restrict__ w3tp,
    const float* __restrict__ b3r, const float* __restrict__ b3t,
    const u16* __restrict__ h1t,             // stride 1280
    const float* __restrict__ w4r, const float* __restrict__ b4r,
    const float* __restrict__ w4t, const float* __restrict__ b4t,
    const int* __restrict__ objp, float* __restrict__ out)
{
    __shared__ __align__(16) u16 smem[27680];
    u16* const lds_a  = smem;                    // dbuf: +cur*8192
    u16* const lds_b  = smem + 16384;            // dbuf: +cur*1024
    u16* const h2     = smem + 18432;            // 8 panels x [32 rows][32 k]
    float* const ldsw = (float*)(smem + 26624);  // 4 x 132 f32
    float* const h3buf = (float*)smem;           // 32 x 132 f32 (overlay on A)

    const int t = threadIdx.x;
    const int n0 = blockIdx.x * 32;
    const int w = t >> 6, l = t & 63;
    const int sr = l >> 2, sc = (l & 3) * 8;
    const int lrow = l & 15, quad = l >> 4;
    const int o = objp[0];

    for (int br = 0; br < 2; ++br) {
        const u16* w2p = br ? w2tp : w2rp;
        const float* b2 = br ? b2t : b2r;
        const u16* w3p = br ? w3tp : w3rp;
        const float* b3 = br ? b3t : b3r;
        const float* w4 = br ? w4t : w4r;
        const int NR = br ? 3 : 4;

        // ===== phase 2: h2[32][256] =====
        const u16* gA0 = w2p + (size_t)(w * 64 +      sr) * 640 + sc;
        const u16* gA1 = w2p + (size_t)(w * 64 + 16 + sr) * 640 + sc;
        const u16* gA2 = w2p + (size_t)(w * 64 + 32 + sr) * 640 + sc;
        const u16* gA3 = w2p + (size_t)(w * 64 + 48 + sr) * 640 + sc;
        const u16* gB0 = h1t + (size_t)(n0 + w * 16 + sr) * 1280 + br * 640 + sc;

        f32x4 acc2[4][2];
#pragma unroll
        for (int i = 0; i < 4; ++i)
#pragma unroll
            for (int j = 0; j < 2; ++j)
                acc2[i][j] = (f32x4){0.f, 0.f, 0.f, 0.f};

        {
            u16* lA = lds_a + w * 2048;
            ld_lds16(gA0, lA);        ld_lds16(gA1, lA + 512);
            ld_lds16(gA2, lA + 1024); ld_lds16(gA3, lA + 1536);
            if (w < 2) ld_lds16(gB0, lds_b + w * 512);
        }
        __syncthreads();

        int cur = 0;
        for (int kt = 0; kt < 640; kt += 32) {
            if (kt + 32 < 640) {
                gA0 += 32; gA1 += 32; gA2 += 32; gA3 += 32; gB0 += 32;
                u16* lA = lds_a + (cur ^ 1) * 8192 + w * 2048;
                ld_lds16(gA0, lA);        ld_lds16(gA1, lA + 512);
                ld_lds16(gA2, lA + 1024); ld_lds16(gA3, lA + 1536);
                if (w < 2) ld_lds16(gB0, lds_b + (cur ^ 1) * 1024 + w * 512);
            }
            const u16* fa = lds_a + cur * 8192 + (w * 64 + lrow) * 32 + quad * 8;
            const u16* fb = lds_b + cur * 1024 + lrow * 32 + quad * 8;
            bf16x8 af[4], bv[2];
#pragma unroll
            for (int i = 0; i < 4; ++i) af[i] = *(const bf16x8*)(fa + i * 512);
#pragma unroll
            for (int j = 0; j < 2; ++j) bv[j] = *(const bf16x8*)(fb + j * 512);
#pragma unroll
            for (int i = 0; i < 4; ++i)
#pragma unroll
                for (int j = 0; j < 2; ++j)
                    acc2[i][j] = __builtin_amdgcn_mfma_f32_16x16x32_bf16(
                        af[i], bv[j], acc2[i][j], 0, 0, 0);
            __syncthreads();
            cur ^= 1;
        }

        // epilogue: h2 -> panels (panel = m>>5, within-panel [row n][m&31])
#pragma unroll
        for (int i = 0; i < 4; ++i) {
            const int mb = w * 64 + i * 16 + quad * 4;
            const float4 bbv = *(const float4*)&b2[mb];
#pragma unroll
            for (int j = 0; j < 2; ++j) {
                const int nl = j * 16 + lrow;
                f32x4 v = acc2[i][j];
                ushort4 ov;
                ov.x = f2b(fmaxf(v[0] + bbv.x, 0.f));
                ov.y = f2b(fmaxf(v[1] + bbv.y, 0.f));
                ov.z = f2b(fmaxf(v[2] + bbv.z, 0.f));
                ov.w = f2b(fmaxf(v[3] + bbv.w, 0.f));
                *(ushort4*)&h2[(mb >> 5) * 1024 + nl * 32 + (mb & 31)] = ov;
            }
        }
        // obj-selected w4 rows for this branch
        if (t < 128) {
#pragma unroll
            for (int r = 0; r < 4; ++r)
                if (r < NR) ldsw[r * 132 + t] = w4[(size_t)(o * NR + r) * 128 + t];
        }

        // ===== phase 3: h3[32][128] =====
        const u16* gW0 = w3p + (size_t)(w * 32 +      sr) * 256 + sc;
        const u16* gW1 = w3p + (size_t)(w * 32 + 16 + sr) * 256 + sc;

        f32x4 acc3[2][2];
#pragma unroll
        for (int i = 0; i < 2; ++i)
#pragma unroll
            for (int j = 0; j < 2; ++j)
                acc3[i][j] = (f32x4){0.f, 0.f, 0.f, 0.f};

        {
            u16* lA = lds_a + w * 1024;
            ld_lds16(gW0, lA); ld_lds16(gW1, lA + 512);
        }
        __syncthreads();   // staging + h2 epilogue + ldsw visible

        cur = 0;
        for (int kt = 0; kt < 256; kt += 32) {
            if (kt + 32 < 256) {
                gW0 += 32; gW1 += 32;
                u16* lA = lds_a + (cur ^ 1) * 8192 + w * 1024;
                ld_lds16(gW0, lA); ld_lds16(gW1, lA + 512);
            }
            const u16* fa = lds_a + cur * 8192 + (w * 32 + lrow) * 32 + quad * 8;
            const u16* fb = h2 + (kt >> 5) * 1024 + lrow * 32 + quad * 8;
            bf16x8 af[2], bv[2];
            af[0] = *(const bf16x8*)(fa);
            af[1] = *(const bf16x8*)(fa + 512);
            bv[0] = *(const bf16x8*)(fb);
            bv[1] = *(const bf16x8*)(fb + 512);
#pragma unroll
            for (int i = 0; i < 2; ++i)
#pragma unroll
                for (int j = 0; j < 2; ++j)
                    acc3[i][j] = __builtin_amdgcn_mfma_f32_16x16x32_bf16(
                        af[i], bv[j], acc3[i][j], 0, 0, 0);
            __syncthreads();
            cur ^= 1;
        }

        // epilogue: h3 (f32, relu) -> h3buf (safe: all A reads pre-barrier)
#pragma unroll
        for (int i = 0; i < 2; ++i) {
            const int mb = w * 32 + i * 16 + quad * 4;
            const float4 bbv = *(const float4*)&b3[mb];
#pragma unroll
            for (int j = 0; j < 2; ++j) {
                const int nl = j * 16 + lrow;
                f32x4 v = acc3[i][j];
                float4 x;
                x.x = fmaxf(v[0] + bbv.x, 0.f); x.y = fmaxf(v[1] + bbv.y, 0.f);
                x.z = fmaxf(v[2] + bbv.z, 0.f); x.w = fmaxf(v[3] + bbv.w, 0.f);
                *(float4*)&h3buf[nl * 132 + mb] = x;
            }
        }
        __syncthreads();

        // ===== final: layer 4 (thread t -> n_local = t>>2, k = t&3) =====
        {
            const int nl = t >> 2, k = t & 3;
            if (t < 128 && k < NR) {
                const float4* hp  = (const float4*)&h3buf[nl * 132];
                const float4* wp4 = (const float4*)&ldsw[k * 132];
                float s = 0.f;
#pragma unroll
                for (int m4 = 0; m4 < 32; ++m4) {
                    float4 h = hp[m4], ww = wp4[m4];
                    s = fmaf(h.x, ww.x, s); s = fmaf(h.y, ww.y, s);
                    s = fmaf(h.z, ww.z, s); s = fmaf(h.w, ww.w, s);
                }
                const int n = n0 + nl;
                if (br == 0) out[(size_t)n * 4 + k] = s + b4r[o * 4 + k];
                else         out[32768 + (size_t)n * 3 + k] = s + b4t[o * 3 + k];
            }
        }
        __syncthreads();   // final done before next branch reuses LDS
    }
}

// ---------------------------------------------------------------------------
extern "C" void kernel_launch(void* const* d_in, const int* in_sizes, int n_in,
                              void* d_out, int out_size, void* d_ws, size_t ws_size,
                              hipStream_t stream)
{
    const float* emb1 = (const float*)d_in[0];
    const float* emb2 = (const float*)d_in[1];
    const float* t1   = (const float*)d_in[2];
    const float* t2   = (const float*)d_in[3];
    const int*   obj  = (const int*)d_in[4];
    const float* w1r = (const float*)d_in[5];  const float* b1r = (const float*)d_in[6];
    const float* w2r = (const float*)d_in[7];  const float* b2r = (const float*)d_in[8];
    const float* w3r = (const float*)d_in[9];  const float* b3r = (const float*)d_in[10];
    const float* w4r = (const float*)d_in[11]; const float* b4r = (const float*)d_in[12];
    const float* w1t = (const float*)d_in[13]; const float* b1t = (const float*)d_in[14];
    const float* w2t = (const float*)d_in[15]; const float* b2t = (const float*)d_in[16];
    const float* w3t = (const float*)d_in[17]; const float* b3t = (const float*)d_in[18];
    const float* w4t = (const float*)d_in[19]; const float* b4t = (const float*)d_in[20];

    char* ws = (char*)d_ws;
    u64* part  = (u64*)(ws + (1u << 16));                        // 4 MB (64 x 8192 keys)
    u16* emb1t = (u16*)(ws + (8u << 20));                        // 8 MB  (8192x512)
    u16* emb2t = (u16*)(ws + (16u << 20));                       // 8 MB  (8192x512)
    u16* h1t   = (u16*)(ws + (24u << 20));                       // 20 MB (8192x1280)
    u16* wp    = (u16*)(ws + (44u << 20));                       // 3.25 MB packed weights

    u16* w1rp = wp;            u16* w1tp = wp + 655360;
    u16* w2rp = wp + 1310720;  u16* w2tp = wp + 1474560;
    u16* w3rp = wp + 1638400;  u16* w3tp = wp + 1671168;

    prep_k<<<PREP_TRANS_END, 256, 0, stream>>>(w1r, w1t, w2r, w2t, w3r, w3t, wp,
                                               t1, t2, part,
                                               emb1, emb2, emb1t, emb2t);
    gemm1_k<<<dim3(64, 5, 2), 256, 0, stream>>>(w1rp, w1tp, b1r, b1t,
                                                emb1t, emb2t, part, h1t);
    gemm23_k<<<256, 256, 0, stream>>>(w2rp, w2tp, b2r, b2t, w3rp, w3tp, b3r, b3t,
                                      h1t, w4r, b4r, w4t, b4t, obj, (float*)d_out);
}

// Round 9
// 197.000 us; speedup vs baseline: 1.0341x; 1.0341x over previous
//
#include <hip/hip_runtime.h>

typedef unsigned short u16;
typedef unsigned long long u64;
typedef __bf16 bf16x8 __attribute__((ext_vector_type(8)));
typedef float f32x4 __attribute__((ext_vector_type(4)));

__device__ __forceinline__ u16 f2b(float f) {
    unsigned int u = __float_as_uint(f);
    u += 0x7fffu + ((u >> 16) & 1u);   // RNE
    return (u16)(u >> 16);
}

// async global->LDS, 16B per lane; LDS dest is wave-uniform base + lane*16B.
__device__ __forceinline__ void ld_lds16(const u16* g, u16* l) {
    __builtin_amdgcn_global_load_lds(
        (__attribute__((address_space(1))) void*)(uintptr_t)(const void*)g,
        (__attribute__((address_space(3))) void*)l, 16, 0, 0);
}

// ---------------------------------------------------------------------------
// Fused prologue: three independent jobs in one dispatch (block-role switch).
//   blocks [0,832):      weight pack f32->bf16
//   blocks [832,1344):   knn phase-1 (per-slab best, NO atomics)
//   blocks [1344,3392):  transpose emb1->emb1t, emb2->emb2t (f32 -> bf16)
// ---------------------------------------------------------------------------
#define PREP_PACK_END  832
#define PREP_KNN_END   1344   // 64 ref-slabs x 8 query-blocks
#define PREP_TRANS_END 3392   // 128 n-tiles x 8 f-tiles x 2 sources

__global__ __launch_bounds__(256) void prep_k(
    const float* __restrict__ w1r, const float* __restrict__ w1t,
    const float* __restrict__ w2r, const float* __restrict__ w2t,
    const float* __restrict__ w3r, const float* __restrict__ w3t,
    u16* __restrict__ wdst,
    const float* __restrict__ t1, const float* __restrict__ t2,
    u64* __restrict__ part,
    const float* __restrict__ e1, const float* __restrict__ e2,
    u16* __restrict__ o1, u16* __restrict__ o2)
{
    __shared__ __align__(16) float smem[64 * 65];
    const int bid = blockIdx.x;
    const int t = threadIdx.x;

    if (bid < PREP_PACK_END) {
        // ---- weight pack: [w1r|w1t|w2r|w2t|w3r|w3t] -> bf16 ----
        size_t i = (size_t)bid * 2048 + (size_t)t * 8;
        const float* src; size_t off;
        if (i < 655360)       { src = w1r; off = 0; }
        else if (i < 1310720) { src = w1t; off = 655360; }
        else if (i < 1474560) { src = w2r; off = 1310720; }
        else if (i < 1638400) { src = w2t; off = 1474560; }
        else if (i < 1671168) { src = w3r; off = 1638400; }
        else                  { src = w3t; off = 1671168; }
        const float4 lo = *(const float4*)(src + (i - off));
        const float4 hi = *(const float4*)(src + (i - off) + 4);
        ushort4 o0v, o1v;
        o0v.x = f2b(lo.x); o0v.y = f2b(lo.y); o0v.z = f2b(lo.z); o0v.w = f2b(lo.w);
        o1v.x = f2b(hi.x); o1v.y = f2b(hi.y); o1v.z = f2b(hi.z); o1v.w = f2b(hi.w);
        *(ushort4*)(wdst + i) = o0v;
        *(ushort4*)(wdst + i + 4) = o1v;
    } else if (bid < PREP_KNN_END) {
        // ---- knn phase-1: slab rs (128 refs), query-block qb (1024 queries) ----
        float4* ref = (float4*)smem;
        const int rb = bid - PREP_PACK_END;
        const int rs = rb & 63;
        const int qb = rb >> 6;
        if (t < 128) {
            int i = rs * 128 + t;
            float x = t1[i], y = t1[8192 + i], z = t1[16384 + i];
            float rr = __fadd_rn(__fadd_rn(__fmul_rn(x, x), __fmul_rn(y, y)), __fmul_rn(z, z));
            ref[t] = make_float4(x, y, z, rr);
        }
        __syncthreads();

        float qx[4], qy[4], qz[4], qq[4], bestd[4];
        int besti[4];
        const int q0 = qb * 1024 + t;
#pragma unroll
        for (int j = 0; j < 4; ++j) {
            int q = q0 + j * 256;
            qx[j] = t2[q]; qy[j] = t2[8192 + q]; qz[j] = t2[16384 + q];
            qq[j] = __fadd_rn(__fadd_rn(__fmul_rn(qx[j], qx[j]), __fmul_rn(qy[j], qy[j])),
                              __fmul_rn(qz[j], qz[j]));
            bestd[j] = __uint_as_float(0x7f800000u);
            besti[j] = 0;
        }
        for (int i = 0; i < 128; ++i) {
            float4 r = ref[i];
#pragma unroll
            for (int j = 0; j < 4; ++j) {
                float g = __fmaf_rn(qz[j], r.z, __fmaf_rn(qy[j], r.y, __fmul_rn(qx[j], r.x)));
                float d2 = __fsub_rn(__fadd_rn(r.w, qq[j]), __fmul_rn(2.0f, g));
                if (d2 < bestd[j]) { bestd[j] = d2; besti[j] = i + rs * 128; }
            }
        }
#pragma unroll
        for (int j = 0; j < 4; ++j) {
            u64 key = ((u64)__float_as_uint(bestd[j]) << 32) | (unsigned int)besti[j];
            part[(size_t)rs * 8192 + q0 + j * 256] = key;
        }
    } else {
        // ---- transpose: z=0 emb1->emb1t, z=1 emb2->emb2t (both stride 512) ----
        float (*tile)[65] = (float(*)[65])smem;
        const int tb = bid - PREP_KNN_END;
        const int z = tb >> 10;
        const int rem = tb & 1023;
        const int fy = rem >> 7;      // 8 f-tiles
        const int nx = rem & 127;     // 128 n-tiles
        const float* in = z ? e2 : e1;
        u16* out = z ? o2 : o1;
        const int n0 = nx * 64, f0 = fy * 64;
        const int c = t & 63, r4 = t >> 6;
#pragma unroll
        for (int p = 0; p < 16; ++p) {
            int fr = p * 4 + r4;
            tile[fr][c] = in[(size_t)(f0 + fr) * 8192 + n0 + c];
        }
        __syncthreads();
        const int fc = (t & 15) * 4;    // f-chunk of 4
        const int nr4 = t >> 4;         // 16 n-rows covered per pass
#pragma unroll
        for (int p = 0; p < 4; ++p) {
            int nr = p * 16 + nr4;
            ushort4 o;
            o.x = f2b(tile[fc + 0][nr]); o.y = f2b(tile[fc + 1][nr]);
            o.z = f2b(tile[fc + 2][nr]); o.w = f2b(tile[fc + 3][nr]);
            *(ushort4*)&out[(size_t)(n0 + nr) * 512 + f0 + fc] = o;
        }
    }
}

// ---------------------------------------------------------------------------
// Layer 1 GEMM, TN=128 / BK=64 (two 32-col panels per barrier pair) — the
// round-6 best-measured structure (45.9us). Depth-1/depth-2 source pipelining
// both regressed (R7: 47.5, R8: 66.8) -> schedule mining closed.
// Fused: in-block knn slab-reduce + gather:
//   B row n: k<512 -> emb1t[idx[n]][k] ; k>=512 -> emb2t[n][k-512]
// ---------------------------------------------------------------------------
__global__ __launch_bounds__(256) void gemm1_k(
    const u16* __restrict__ Ar, const u16* __restrict__ At,
    const float* __restrict__ biasr, const float* __restrict__ biast,
    const u16* __restrict__ emb1t, const u16* __restrict__ emb2t,
    const u64* __restrict__ part,
    u16* __restrict__ Ct)                    // h1t, stride 1280
{
    constexpr int K = 1024;
    // panel p at offset p*4096 (u16); per-panel layout identical to BK=32 ver.
    __shared__ __align__(16) u16 lds_a[2 * 128 * 32];
    __shared__ __align__(16) u16 lds_b[2 * 128 * 32];
    __shared__ u64 red[2][128];
    __shared__ unsigned int idx_l[128];

    const int t = threadIdx.x;
    const int n0 = blockIdx.x * 128;
    const int m0 = blockIdx.y * 128;
    const int branch = blockIdx.z;

    const u16* A = branch ? At : Ar;
    const float* bias = branch ? biast : biasr;
    const int out_off = branch * 640;

    const int w = t >> 6, l = t & 63;
    const int sr = l >> 2, sc = (l & 3) * 8;

    // ---- in-block knn reduce: idx for rows [n0, n0+128) ----
    {
        const int rrow = t & 127, rhalf = t >> 7;   // 2 threads/row, 32 slabs each
        const u64* pp = part + (size_t)rhalf * 32 * 8192 + (n0 + rrow);
        u64 best = ~0ull;
#pragma unroll 8
        for (int s = 0; s < 32; ++s) {
            u64 k = pp[(size_t)s * 8192];
            best = k < best ? k : best;
        }
        red[rhalf][rrow] = best;
    }
    __syncthreads();
    if (t < 128) {
        u64 a = red[0][t], b = red[1][t];
        idx_l[t] = (unsigned int)(a < b ? a : b);
    }
    __syncthreads();

    const u16* gA0 = A + (size_t)(m0 + w * 32 + sr) * K + sc;
    const u16* gA1 = gA0 + (size_t)16 * K;
    u16* lA = &lds_a[w * 1024];          // +512 for the +16-row half; +4096 panel 1

    const int row0 = n0 + w * 32 + sr;
    const int row1 = row0 + 16;
    const u16* gB0 = emb1t + (size_t)idx_l[w * 32 + sr] * 512 + sc;
    const u16* gB1 = emb1t + (size_t)idx_l[w * 32 + sr + 16] * 512 + sc;
    u16* lB = &lds_b[w * 1024];

    const int wm = (w & 1) * 64;
    const int wn = (w >> 1) * 64;
    const int lrow = l & 15, quad = l >> 4;
    const u16* fa = &lds_a[(wm + lrow) * 32 + quad * 8];
    const u16* fb = &lds_b[(wn + lrow) * 32 + quad * 8];

    f32x4 acc[4][4];
#pragma unroll
    for (int i = 0; i < 4; ++i)
#pragma unroll
        for (int j = 0; j < 4; ++j)
            acc[i][j] = (f32x4){0.f, 0.f, 0.f, 0.f};

    // prologue: stage kt=0 (panels 0,1 = k 0..31, 32..63; all emb1 region)
    ld_lds16(gA0,      lA);
    ld_lds16(gA1,      lA + 512);
    ld_lds16(gA0 + 32, lA + 4096);
    ld_lds16(gA1 + 32, lA + 4096 + 512);
    ld_lds16(gB0,      lB);
    ld_lds16(gB1,      lB + 512);
    ld_lds16(gB0 + 32, lB + 4096);
    ld_lds16(gB1 + 32, lB + 4096 + 512);

    for (int kt = 0; kt < K; kt += 64) {
        __syncthreads();
        bf16x8 af[2][4], bfr[2][4];
#pragma unroll
        for (int p = 0; p < 2; ++p)
#pragma unroll
            for (int i = 0; i < 4; ++i) {
                af[p][i]  = *(const bf16x8*)(fa + p * 4096 + i * 16 * 32);
                bfr[p][i] = *(const bf16x8*)(fb + p * 4096 + i * 16 * 32);
            }
        __syncthreads();
        if (kt + 64 < K) {
            gA0 += 64; gA1 += 64;
            if (kt + 64 == 512) {   // switch B source: emb1 gather -> emb2 direct
                gB0 = emb2t + (size_t)row0 * 512 + sc;
                gB1 = emb2t + (size_t)row1 * 512 + sc;
            } else {
                gB0 += 64; gB1 += 64;
            }
            ld_lds16(gA0,      lA);
            ld_lds16(gA1,      lA + 512);
            ld_lds16(gA0 + 32, lA + 4096);
            ld_lds16(gA1 + 32, lA + 4096 + 512);
            ld_lds16(gB0,      lB);
            ld_lds16(gB1,      lB + 512);
            ld_lds16(gB0 + 32, lB + 4096);
            ld_lds16(gB1 + 32, lB + 4096 + 512);
        }
#pragma unroll
        for (int p = 0; p < 2; ++p)
#pragma unroll
            for (int i = 0; i < 4; ++i)
#pragma unroll
                for (int j = 0; j < 4; ++j)
                    acc[i][j] = __builtin_amdgcn_mfma_f32_16x16x32_bf16(
                        af[p][i], bfr[p][j], acc[i][j], 0, 0, 0);
    }

    // epilogue: D row m = quad*4+reg, col n = lrow; relu always
#pragma unroll
    for (int i = 0; i < 4; ++i) {
        const int mbase = m0 + wm + i * 16 + quad * 4;
        const float4 bbv = *(const float4*)&bias[mbase];
#pragma unroll
        for (int j = 0; j < 4; ++j) {
            const int n = n0 + wn + j * 16 + lrow;
            f32x4 v = acc[i][j];
            float x0 = fmaxf(v[0] + bbv.x, 0.f);
            float x1 = fmaxf(v[1] + bbv.y, 0.f);
            float x2 = fmaxf(v[2] + bbv.z, 0.f);
            float x3 = fmaxf(v[3] + bbv.w, 0.f);
            ushort4 o;
            o.x = f2b(x0); o.y = f2b(x1); o.z = f2b(x2); o.w = f2b(x3);
            *(ushort4*)&Ct[(size_t)n * 1280 + out_off + mbase] = o;
        }
    }
}

// ---------------------------------------------------------------------------
// Fused layers 2+3+4: grid (256, 2) -> block = (32-row n-tile, branch).
// R7 ran both branches serially in one block (1 block/CU); branch is
// independent, so parallelize it: 512 blocks = 2 blocks/CU, ~halving dur.
//   phase 2: h2[32][256] = relu(w2 . h1seg + b2)  -> LDS panels (bf16)
//   phase 3: h3[32][128] = relu(w3 . h2 + b3)     -> LDS f32 (overlays A-buf)
//   final  : obj-selected w4 rows (NR=4/3) dot h3 -> out
// LDS map (u16 units): A dbuf [0,16384) | B dbuf [16384,18432) |
//   h2 [18432,26624) | w4 [26624,27680). h3buf (f32) overlays A.
// ---------------------------------------------------------------------------
__global__ __launch_bounds__(256) void gemm23_k(
    const u16* __restrict__ w2rp, const u16* __restrict__ w2tp,
    const float* __restrict__ b2r, const float* __restrict__ b2t,
    const u16* __restrict__ w3rp, const u16* __restrict__ w3tp,
    const float* __restrict__ b3r, const float* __restrict__ b3t,
    const u16* __restrict__ h1t,             // stride 1280
    const float* __restrict__ w4r, const float* __restrict__ b4r,
    const float* __restrict__ w4t, const float* __restrict__ b4t,
    const int* __restrict__ objp, float* __restrict__ out)
{
    __shared__ __align__(16) u16 smem[27680];
    u16* const lds_a  = smem;                    // dbuf: +cur*8192
    u16* const lds_b  = smem + 16384;            // dbuf: +cur*1024
    u16* const h2     = smem + 18432;            // 8 panels x [32 rows][32 k]
    float* const ldsw = (float*)(smem + 26624);  // 4 x 132 f32
    float* const h3buf = (float*)smem;           // 32 x 132 f32 (overlay on A)

    const int t = threadIdx.x;
    const int n0 = blockIdx.x * 32;
    const int br = blockIdx.y;
    const int w = t >> 6, l = t & 63;
    const int sr = l >> 2, sc = (l & 3) * 8;
    const int lrow = l & 15, quad = l >> 4;
    const int o = objp[0];

    const u16* w2p = br ? w2tp : w2rp;
    const float* b2 = br ? b2t : b2r;
    const u16* w3p = br ? w3tp : w3rp;
    const float* b3 = br ? b3t : b3r;
    const float* w4 = br ? w4t : w4r;
    const int NR = br ? 3 : 4;

    // ===== phase 2: h2[32][256] =====
    const u16* gA0 = w2p + (size_t)(w * 64 +      sr) * 640 + sc;
    const u16* gA1 = w2p + (size_t)(w * 64 + 16 + sr) * 640 + sc;
    const u16* gA2 = w2p + (size_t)(w * 64 + 32 + sr) * 640 + sc;
    const u16* gA3 = w2p + (size_t)(w * 64 + 48 + sr) * 640 + sc;
    const u16* gB0 = h1t + (size_t)(n0 + w * 16 + sr) * 1280 + br * 640 + sc;

    f32x4 acc2[4][2];
#pragma unroll
    for (int i = 0; i < 4; ++i)
#pragma unroll
        for (int j = 0; j < 2; ++j)
            acc2[i][j] = (f32x4){0.f, 0.f, 0.f, 0.f};

    {
        u16* lA = lds_a + w * 2048;
        ld_lds16(gA0, lA);        ld_lds16(gA1, lA + 512);
        ld_lds16(gA2, lA + 1024); ld_lds16(gA3, lA + 1536);
        if (w < 2) ld_lds16(gB0, lds_b + w * 512);
    }
    __syncthreads();

    int cur = 0;
    for (int kt = 0; kt < 640; kt += 32) {
        if (kt + 32 < 640) {
            gA0 += 32; gA1 += 32; gA2 += 32; gA3 += 32; gB0 += 32;
            u16* lA = lds_a + (cur ^ 1) * 8192 + w * 2048;
            ld_lds16(gA0, lA);        ld_lds16(gA1, lA + 512);
            ld_lds16(gA2, lA + 1024); ld_lds16(gA3, lA + 1536);
            if (w < 2) ld_lds16(gB0, lds_b + (cur ^ 1) * 1024 + w * 512);
        }
        const u16* fa = lds_a + cur * 8192 + (w * 64 + lrow) * 32 + quad * 8;
        const u16* fb = lds_b + cur * 1024 + lrow * 32 + quad * 8;
        bf16x8 af[4], bv[2];
#pragma unroll
        for (int i = 0; i < 4; ++i) af[i] = *(const bf16x8*)(fa + i * 512);
#pragma unroll
        for (int j = 0; j < 2; ++j) bv[j] = *(const bf16x8*)(fb + j * 512);
#pragma unroll
        for (int i = 0; i < 4; ++i)
#pragma unroll
            for (int j = 0; j < 2; ++j)
                acc2[i][j] = __builtin_amdgcn_mfma_f32_16x16x32_bf16(
                    af[i], bv[j], acc2[i][j], 0, 0, 0);
        __syncthreads();
        cur ^= 1;
    }

    // epilogue: h2 -> panels (panel = m>>5, within-panel [row n][m&31])
#pragma unroll
    for (int i = 0; i < 4; ++i) {
        const int mb = w * 64 + i * 16 + quad * 4;
        const float4 bbv = *(const float4*)&b2[mb];
#pragma unroll
        for (int j = 0; j < 2; ++j) {
            const int nl = j * 16 + lrow;
            f32x4 v = acc2[i][j];
            ushort4 ov;
            ov.x = f2b(fmaxf(v[0] + bbv.x, 0.f));
            ov.y = f2b(fmaxf(v[1] + bbv.y, 0.f));
            ov.z = f2b(fmaxf(v[2] + bbv.z, 0.f));
            ov.w = f2b(fmaxf(v[3] + bbv.w, 0.f));
            *(ushort4*)&h2[(mb >> 5) * 1024 + nl * 32 + (mb & 31)] = ov;
        }
    }
    // obj-selected w4 rows for this branch
    if (t < 128) {
#pragma unroll
        for (int r = 0; r < 4; ++r)
            if (r < NR) ldsw[r * 132 + t] = w4[(size_t)(o * NR + r) * 128 + t];
    }

    // ===== phase 3: h3[32][128] =====
    const u16* gW0 = w3p + (size_t)(w * 32 +      sr) * 256 + sc;
    const u16* gW1 = w3p + (size_t)(w * 32 + 16 + sr) * 256 + sc;

    f32x4 acc3[2][2];
#pragma unroll
    for (int i = 0; i < 2; ++i)
#pragma unroll
        for (int j = 0; j < 2; ++j)
            acc3[i][j] = (f32x4){0.f, 0.f, 0.f, 0.f};

    {
        u16* lA = lds_a + w * 1024;
        ld_lds16(gW0, lA); ld_lds16(gW1, lA + 512);
    }
    __syncthreads();   // staging + h2 epilogue + ldsw visible

    cur = 0;
    for (int kt = 0; kt < 256; kt += 32) {
        if (kt + 32 < 256) {
            gW0 += 32; gW1 += 32;
            u16* lA = lds_a + (cur ^ 1) * 8192 + w * 1024;
            ld_lds16(gW0, lA); ld_lds16(gW1, lA + 512);
        }
        const u16* fa = lds_a + cur * 8192 + (w * 32 + lrow) * 32 + quad * 8;
        const u16* fb = h2 + (kt >> 5) * 1024 + lrow * 32 + quad * 8;
        bf16x8 af[2], bv[2];
        af[0] = *(const bf16x8*)(fa);
        af[1] = *(const bf16x8*)(fa + 512);
        bv[0] = *(const bf16x8*)(fb);
        bv[1] = *(const bf16x8*)(fb + 512);
#pragma unroll
        for (int i = 0; i < 2; ++i)
#pragma unroll
            for (int j = 0; j < 2; ++j)
                acc3[i][j] = __builtin_amdgcn_mfma_f32_16x16x32_bf16(
                    af[i], bv[j], acc3[i][j], 0, 0, 0);
        __syncthreads();
        cur ^= 1;
    }

    // epilogue: h3 (f32, relu) -> h3buf (safe: all A reads pre-barrier)
#pragma unroll
    for (int i = 0; i < 2; ++i) {
        const int mb = w * 32 + i * 16 + quad * 4;
        const float4 bbv = *(const float4*)&b3[mb];
#pragma unroll
        for (int j = 0; j < 2; ++j) {
            const int nl = j * 16 + lrow;
            f32x4 v = acc3[i][j];
            float4 x;
            x.x = fmaxf(v[0] + bbv.x, 0.f); x.y = fmaxf(v[1] + bbv.y, 0.f);
            x.z = fmaxf(v[2] + bbv.z, 0.f); x.w = fmaxf(v[3] + bbv.w, 0.f);
            *(float4*)&h3buf[nl * 132 + mb] = x;
        }
    }
    __syncthreads();

    // ===== final: layer 4 (thread t -> n_local = t>>2, k = t&3) =====
    {
        const int nl = t >> 2, k = t & 3;
        if (t < 128 && k < NR) {
            const float4* hp  = (const float4*)&h3buf[nl * 132];
            const float4* wp4 = (const float4*)&ldsw[k * 132];
            float s = 0.f;
#pragma unroll
            for (int m4 = 0; m4 < 32; ++m4) {
                float4 h = hp[m4], ww = wp4[m4];
                s = fmaf(h.x, ww.x, s); s = fmaf(h.y, ww.y, s);
                s = fmaf(h.z, ww.z, s); s = fmaf(h.w, ww.w, s);
            }
            const int n = n0 + nl;
            if (br == 0) out[(size_t)n * 4 + k] = s + b4r[o * 4 + k];
            else         out[32768 + (size_t)n * 3 + k] = s + b4t[o * 3 + k];
        }
    }
}

// ---------------------------------------------------------------------------
extern "C" void kernel_launch(void* const* d_in, const int* in_sizes, int n_in,
                              void* d_out, int out_size, void* d_ws, size_t ws_size,
                              hipStream_t stream)
{
    const float* emb1 = (const float*)d_in[0];
    const float* emb2 = (const float*)d_in[1];
    const float* t1   = (const float*)d_in[2];
    const float* t2   = (const float*)d_in[3];
    const int*   obj  = (const int*)d_in[4];
    const float* w1r = (const float*)d_in[5];  const float* b1r = (const float*)d_in[6];
    const float* w2r = (const float*)d_in[7];  const float* b2r = (const float*)d_in[8];
    const float* w3r = (const float*)d_in[9];  const float* b3r = (const float*)d_in[10];
    const float* w4r = (const float*)d_in[11]; const float* b4r = (const float*)d_in[12];
    const float* w1t = (const float*)d_in[13]; const float* b1t = (const float*)d_in[14];
    const float* w2t = (const float*)d_in[15]; const float* b2t = (const float*)d_in[16];
    const float* w3t = (const float*)d_in[17]; const float* b3t = (const float*)d_in[18];
    const float* w4t = (const float*)d_in[19]; const float* b4t = (const float*)d_in[20];

    char* ws = (char*)d_ws;
    u64* part  = (u64*)(ws + (1u << 16));                        // 4 MB (64 x 8192 keys)
    u16* emb1t = (u16*)(ws + (8u << 20));                        // 8 MB  (8192x512)
    u16* emb2t = (u16*)(ws + (16u << 20));                       // 8 MB  (8192x512)
    u16* h1t   = (u16*)(ws + (24u << 20));                       // 20 MB (8192x1280)
    u16* wp    = (u16*)(ws + (44u << 20));                       // 3.25 MB packed weights

    u16* w1rp = wp;            u16* w1tp = wp + 655360;
    u16* w2rp = wp + 1310720;  u16* w2tp = wp + 1474560;
    u16* w3rp = wp + 1638400;  u16* w3tp = wp + 1671168;

    prep_k<<<PREP_TRANS_END, 256, 0, stream>>>(w1r, w1t, w2r, w2t, w3r, w3t, wp,
                                               t1, t2, part,
                                               emb1, emb2, emb1t, emb2t);
    gemm1_k<<<dim3(64, 5, 2), 256, 0, stream>>>(w1rp, w1tp, b1r, b1t,
                                                emb1t, emb2t, part, h1t);
    gemm23_k<<<dim3(256, 2), 256, 0, stream>>>(w2rp, w2tp, b2r, b2t, w3rp, w3tp, b3r, b3t,
                                               h1t, w4r, b4r, w4t, b4t, obj, (float*)d_out);
}

// Round 10
// 186.457 us; speedup vs baseline: 1.0926x; 1.0565x over previous
//
#include <hip/hip_runtime.h>

typedef unsigned short u16;
typedef unsigned long long u64;
typedef __bf16 bf16x8 __attribute__((ext_vector_type(8)));
typedef float f32x4 __attribute__((ext_vector_type(4)));

__device__ __forceinline__ u16 f2b(float f) {
    unsigned int u = __float_as_uint(f);
    u += 0x7fffu + ((u >> 16) & 1u);   // RNE
    return (u16)(u >> 16);
}

// async global->LDS, 16B per lane; LDS dest is wave-uniform base + lane*16B.
__device__ __forceinline__ void ld_lds16(const u16* g, u16* l) {
    __builtin_amdgcn_global_load_lds(
        (__attribute__((address_space(1))) void*)(uintptr_t)(const void*)g,
        (__attribute__((address_space(3))) void*)l, 16, 0, 0);
}

// ---------------------------------------------------------------------------
// Fused prologue: three independent jobs in one dispatch (block-role switch).
//   blocks [0,832):      weight pack f32->bf16
//   blocks [832,1344):   knn phase-1 (per-slab best, NO atomics)
//   blocks [1344,3392):  transpose emb1->emb1t, emb2->emb2t (f32 -> bf16)
// ---------------------------------------------------------------------------
#define PREP_PACK_END  832
#define PREP_KNN_END   1344   // 64 ref-slabs x 8 query-blocks
#define PREP_TRANS_END 3392   // 128 n-tiles x 8 f-tiles x 2 sources

__global__ __launch_bounds__(256) void prep_k(
    const float* __restrict__ w1r, const float* __restrict__ w1t,
    const float* __restrict__ w2r, const float* __restrict__ w2t,
    const float* __restrict__ w3r, const float* __restrict__ w3t,
    u16* __restrict__ wdst,
    const float* __restrict__ t1, const float* __restrict__ t2,
    u64* __restrict__ part,
    const float* __restrict__ e1, const float* __restrict__ e2,
    u16* __restrict__ o1, u16* __restrict__ o2)
{
    __shared__ __align__(16) float smem[64 * 65];
    const int bid = blockIdx.x;
    const int t = threadIdx.x;

    if (bid < PREP_PACK_END) {
        // ---- weight pack: [w1r|w1t|w2r|w2t|w3r|w3t] -> bf16 ----
        size_t i = (size_t)bid * 2048 + (size_t)t * 8;
        const float* src; size_t off;
        if (i < 655360)       { src = w1r; off = 0; }
        else if (i < 1310720) { src = w1t; off = 655360; }
        else if (i < 1474560) { src = w2r; off = 1310720; }
        else if (i < 1638400) { src = w2t; off = 1474560; }
        else if (i < 1671168) { src = w3r; off = 1638400; }
        else                  { src = w3t; off = 1671168; }
        const float4 lo = *(const float4*)(src + (i - off));
        const float4 hi = *(const float4*)(src + (i - off) + 4);
        ushort4 o0v, o1v;
        o0v.x = f2b(lo.x); o0v.y = f2b(lo.y); o0v.z = f2b(lo.z); o0v.w = f2b(lo.w);
        o1v.x = f2b(hi.x); o1v.y = f2b(hi.y); o1v.z = f2b(hi.z); o1v.w = f2b(hi.w);
        *(ushort4*)(wdst + i) = o0v;
        *(ushort4*)(wdst + i + 4) = o1v;
    } else if (bid < PREP_KNN_END) {
        // ---- knn phase-1: slab rs (128 refs), query-block qb (1024 queries) ----
        float4* ref = (float4*)smem;
        const int rb = bid - PREP_PACK_END;
        const int rs = rb & 63;
        const int qb = rb >> 6;
        if (t < 128) {
            int i = rs * 128 + t;
            float x = t1[i], y = t1[8192 + i], z = t1[16384 + i];
            float rr = __fadd_rn(__fadd_rn(__fmul_rn(x, x), __fmul_rn(y, y)), __fmul_rn(z, z));
            ref[t] = make_float4(x, y, z, rr);
        }
        __syncthreads();

        float qx[4], qy[4], qz[4], qq[4], bestd[4];
        int besti[4];
        const int q0 = qb * 1024 + t;
#pragma unroll
        for (int j = 0; j < 4; ++j) {
            int q = q0 + j * 256;
            qx[j] = t2[q]; qy[j] = t2[8192 + q]; qz[j] = t2[16384 + q];
            qq[j] = __fadd_rn(__fadd_rn(__fmul_rn(qx[j], qx[j]), __fmul_rn(qy[j], qy[j])),
                              __fmul_rn(qz[j], qz[j]));
            bestd[j] = __uint_as_float(0x7f800000u);
            besti[j] = 0;
        }
        for (int i = 0; i < 128; ++i) {
            float4 r = ref[i];
#pragma unroll
            for (int j = 0; j < 4; ++j) {
                float g = __fmaf_rn(qz[j], r.z, __fmaf_rn(qy[j], r.y, __fmul_rn(qx[j], r.x)));
                float d2 = __fsub_rn(__fadd_rn(r.w, qq[j]), __fmul_rn(2.0f, g));
                if (d2 < bestd[j]) { bestd[j] = d2; besti[j] = i + rs * 128; }
            }
        }
#pragma unroll
        for (int j = 0; j < 4; ++j) {
            u64 key = ((u64)__float_as_uint(bestd[j]) << 32) | (unsigned int)besti[j];
            part[(size_t)rs * 8192 + q0 + j * 256] = key;
        }
    } else {
        // ---- transpose: z=0 emb1->emb1t, z=1 emb2->emb2t (both stride 512) ----
        float (*tile)[65] = (float(*)[65])smem;
        const int tb = bid - PREP_KNN_END;
        const int z = tb >> 10;
        const int rem = tb & 1023;
        const int fy = rem >> 7;      // 8 f-tiles
        const int nx = rem & 127;     // 128 n-tiles
        const float* in = z ? e2 : e1;
        u16* out = z ? o2 : o1;
        const int n0 = nx * 64, f0 = fy * 64;
        const int c = t & 63, r4 = t >> 6;
#pragma unroll
        for (int p = 0; p < 16; ++p) {
            int fr = p * 4 + r4;
            tile[fr][c] = in[(size_t)(f0 + fr) * 8192 + n0 + c];
        }
        __syncthreads();
        const int fc = (t & 15) * 4;    // f-chunk of 4
        const int nr4 = t >> 4;         // 16 n-rows covered per pass
#pragma unroll
        for (int p = 0; p < 4; ++p) {
            int nr = p * 16 + nr4;
            ushort4 o;
            o.x = f2b(tile[fc + 0][nr]); o.y = f2b(tile[fc + 1][nr]);
            o.z = f2b(tile[fc + 2][nr]); o.w = f2b(tile[fc + 3][nr]);
            *(ushort4*)&out[(size_t)(n0 + nr) * 512 + f0 + fc] = o;
        }
    }
}

// ---------------------------------------------------------------------------
// Layer 1 GEMM, TN=128 / BK=64 (two 32-col panels per barrier pair) — the
// best-measured structure (R6/R9: 44-46us). Source-level pipelining variants
// all regressed (R7: 47.5, R8: 66.8) -> schedule mining closed.
// Fused: in-block knn slab-reduce + gather:
//   B row n: k<512 -> emb1t[idx[n]][k] ; k>=512 -> emb2t[n][k-512]
// ---------------------------------------------------------------------------
__global__ __launch_bounds__(256) void gemm1_k(
    const u16* __restrict__ Ar, const u16* __restrict__ At,
    const float* __restrict__ biasr, const float* __restrict__ biast,
    const u16* __restrict__ emb1t, const u16* __restrict__ emb2t,
    const u64* __restrict__ part,
    u16* __restrict__ Ct)                    // h1t, stride 1280
{
    constexpr int K = 1024;
    // panel p at offset p*4096 (u16); per-panel layout identical to BK=32 ver.
    __shared__ __align__(16) u16 lds_a[2 * 128 * 32];
    __shared__ __align__(16) u16 lds_b[2 * 128 * 32];
    __shared__ u64 red[2][128];
    __shared__ unsigned int idx_l[128];

    const int t = threadIdx.x;
    const int n0 = blockIdx.x * 128;
    const int m0 = blockIdx.y * 128;
    const int branch = blockIdx.z;

    const u16* A = branch ? At : Ar;
    const float* bias = branch ? biast : biasr;
    const int out_off = branch * 640;

    const int w = t >> 6, l = t & 63;
    const int sr = l >> 2, sc = (l & 3) * 8;

    // ---- in-block knn reduce: idx for rows [n0, n0+128) ----
    {
        const int rrow = t & 127, rhalf = t >> 7;   // 2 threads/row, 32 slabs each
        const u64* pp = part + (size_t)rhalf * 32 * 8192 + (n0 + rrow);
        u64 best = ~0ull;
#pragma unroll 8
        for (int s = 0; s < 32; ++s) {
            u64 k = pp[(size_t)s * 8192];
            best = k < best ? k : best;
        }
        red[rhalf][rrow] = best;
    }
    __syncthreads();
    if (t < 128) {
        u64 a = red[0][t], b = red[1][t];
        idx_l[t] = (unsigned int)(a < b ? a : b);
    }
    __syncthreads();

    const u16* gA0 = A + (size_t)(m0 + w * 32 + sr) * K + sc;
    const u16* gA1 = gA0 + (size_t)16 * K;
    u16* lA = &lds_a[w * 1024];          // +512 for the +16-row half; +4096 panel 1

    const int row0 = n0 + w * 32 + sr;
    const int row1 = row0 + 16;
    const u16* gB0 = emb1t + (size_t)idx_l[w * 32 + sr] * 512 + sc;
    const u16* gB1 = emb1t + (size_t)idx_l[w * 32 + sr + 16] * 512 + sc;
    u16* lB = &lds_b[w * 1024];

    const int wm = (w & 1) * 64;
    const int wn = (w >> 1) * 64;
    const int lrow = l & 15, quad = l >> 4;
    const u16* fa = &lds_a[(wm + lrow) * 32 + quad * 8];
    const u16* fb = &lds_b[(wn + lrow) * 32 + quad * 8];

    f32x4 acc[4][4];
#pragma unroll
    for (int i = 0; i < 4; ++i)
#pragma unroll
        for (int j = 0; j < 4; ++j)
            acc[i][j] = (f32x4){0.f, 0.f, 0.f, 0.f};

    // prologue: stage kt=0 (panels 0,1 = k 0..31, 32..63; all emb1 region)
    ld_lds16(gA0,      lA);
    ld_lds16(gA1,      lA + 512);
    ld_lds16(gA0 + 32, lA + 4096);
    ld_lds16(gA1 + 32, lA + 4096 + 512);
    ld_lds16(gB0,      lB);
    ld_lds16(gB1,      lB + 512);
    ld_lds16(gB0 + 32, lB + 4096);
    ld_lds16(gB1 + 32, lB + 4096 + 512);

    for (int kt = 0; kt < K; kt += 64) {
        __syncthreads();
        bf16x8 af[2][4], bfr[2][4];
#pragma unroll
        for (int p = 0; p < 2; ++p)
#pragma unroll
            for (int i = 0; i < 4; ++i) {
                af[p][i]  = *(const bf16x8*)(fa + p * 4096 + i * 16 * 32);
                bfr[p][i] = *(const bf16x8*)(fb + p * 4096 + i * 16 * 32);
            }
        __syncthreads();
        if (kt + 64 < K) {
            gA0 += 64; gA1 += 64;
            if (kt + 64 == 512) {   // switch B source: emb1 gather -> emb2 direct
                gB0 = emb2t + (size_t)row0 * 512 + sc;
                gB1 = emb2t + (size_t)row1 * 512 + sc;
            } else {
                gB0 += 64; gB1 += 64;
            }
            ld_lds16(gA0,      lA);
            ld_lds16(gA1,      lA + 512);
            ld_lds16(gA0 + 32, lA + 4096);
            ld_lds16(gA1 + 32, lA + 4096 + 512);
            ld_lds16(gB0,      lB);
            ld_lds16(gB1,      lB + 512);
            ld_lds16(gB0 + 32, lB + 4096);
            ld_lds16(gB1 + 32, lB + 4096 + 512);
        }
#pragma unroll
        for (int p = 0; p < 2; ++p)
#pragma unroll
            for (int i = 0; i < 4; ++i)
#pragma unroll
                for (int j = 0; j < 4; ++j)
                    acc[i][j] = __builtin_amdgcn_mfma_f32_16x16x32_bf16(
                        af[p][i], bfr[p][j], acc[i][j], 0, 0, 0);
    }

    // epilogue: D row m = quad*4+reg, col n = lrow; relu always
#pragma unroll
    for (int i = 0; i < 4; ++i) {
        const int mbase = m0 + wm + i * 16 + quad * 4;
        const float4 bbv = *(const float4*)&bias[mbase];
#pragma unroll
        for (int j = 0; j < 4; ++j) {
            const int n = n0 + wn + j * 16 + lrow;
            f32x4 v = acc[i][j];
            float x0 = fmaxf(v[0] + bbv.x, 0.f);
            float x1 = fmaxf(v[1] + bbv.y, 0.f);
            float x2 = fmaxf(v[2] + bbv.z, 0.f);
            float x3 = fmaxf(v[3] + bbv.w, 0.f);
            ushort4 o;
            o.x = f2b(x0); o.y = f2b(x1); o.z = f2b(x2); o.w = f2b(x3);
            *(ushort4*)&Ct[(size_t)n * 1280 + out_off + mbase] = o;
        }
    }
}

// ---------------------------------------------------------------------------
// Layer 2 GEMM (split-pipeline restored, R6 config): TN=64, M=128/block,
// K=640, now with BK=64 two-panel staging (the in-session-verified gemm1
// transform: half the barrier pairs, 2x MFMA per pair). Grid (128, 2, 2).
//   Ct[n][out_off+m] = relu( sum_k A[m][k]*Bt[n][b_off+k] + bias[m] )
// A = w2 packed (256 x 640), Bt = h1t stride 1280, Ct = h2t stride 512.
// ---------------------------------------------------------------------------
__global__ __launch_bounds__(256) void gemm2_k(
    const u16* __restrict__ Ar, const u16* __restrict__ At,
    const float* __restrict__ biasr, const float* __restrict__ biast,
    const u16* __restrict__ Bt, u16* __restrict__ Ct)
{
    constexpr int K = 640;
    __shared__ __align__(16) u16 lds_a[2 * 128 * 32];   // panel p at p*4096
    __shared__ __align__(16) u16 lds_b[2 * 64 * 32];    // panel p at p*2048

    const int t = threadIdx.x;
    const int n0 = blockIdx.x * 64;
    const int m0 = blockIdx.y * 128;
    const int branch = blockIdx.z;

    const u16* A = branch ? At : Ar;
    const float* bias = branch ? biast : biasr;
    const int b_off = branch * 640;
    const int out_off = branch * 256;

    const int w = t >> 6, l = t & 63;
    const int sr = l >> 2, sc = (l & 3) * 8;

    const u16* gA0 = A + (size_t)(m0 + w * 32 + sr) * K + sc;
    const u16* gA1 = gA0 + (size_t)16 * K;
    u16* lA = &lds_a[w * 1024];

    const u16* gB0 = Bt + (size_t)(n0 + w * 16 + sr) * 1280 + b_off + sc;
    u16* lB = &lds_b[w * 512];

    const int wm = (w & 1) * 64;
    const int wn = (w >> 1) * 32;
    const int lrow = l & 15, quad = l >> 4;
    const u16* fa = &lds_a[(wm + lrow) * 32 + quad * 8];
    const u16* fb = &lds_b[(wn + lrow) * 32 + quad * 8];

    f32x4 acc[4][2];
#pragma unroll
    for (int i = 0; i < 4; ++i)
#pragma unroll
        for (int j = 0; j < 2; ++j)
            acc[i][j] = (f32x4){0.f, 0.f, 0.f, 0.f};

    // prologue: stage kt=0 (panels 0,1)
    ld_lds16(gA0,      lA);
    ld_lds16(gA1,      lA + 512);
    ld_lds16(gA0 + 32, lA + 4096);
    ld_lds16(gA1 + 32, lA + 4096 + 512);
    ld_lds16(gB0,      lB);
    ld_lds16(gB0 + 32, lB + 2048);

    for (int kt = 0; kt < K; kt += 64) {
        __syncthreads();
        bf16x8 af[2][4], bfr[2][2];
#pragma unroll
        for (int p = 0; p < 2; ++p) {
#pragma unroll
            for (int i = 0; i < 4; ++i)
                af[p][i] = *(const bf16x8*)(fa + p * 4096 + i * 16 * 32);
#pragma unroll
            for (int j = 0; j < 2; ++j)
                bfr[p][j] = *(const bf16x8*)(fb + p * 2048 + j * 16 * 32);
        }
        __syncthreads();
        if (kt + 64 < K) {
            gA0 += 64; gA1 += 64; gB0 += 64;
            ld_lds16(gA0,      lA);
            ld_lds16(gA1,      lA + 512);
            ld_lds16(gA0 + 32, lA + 4096);
            ld_lds16(gA1 + 32, lA + 4096 + 512);
            ld_lds16(gB0,      lB);
            ld_lds16(gB0 + 32, lB + 2048);
        }
#pragma unroll
        for (int p = 0; p < 2; ++p)
#pragma unroll
            for (int i = 0; i < 4; ++i)
#pragma unroll
                for (int j = 0; j < 2; ++j)
                    acc[i][j] = __builtin_amdgcn_mfma_f32_16x16x32_bf16(
                        af[p][i], bfr[p][j], acc[i][j], 0, 0, 0);
    }

    // epilogue: D row m = quad*4+reg, col n = lrow; relu
#pragma unroll
    for (int i = 0; i < 4; ++i) {
        const int mbase = m0 + wm + i * 16 + quad * 4;
        const float4 bbv = *(const float4*)&bias[mbase];
#pragma unroll
        for (int j = 0; j < 2; ++j) {
            const int n = n0 + wn + j * 16 + lrow;
            f32x4 v = acc[i][j];
            float x0 = fmaxf(v[0] + bbv.x, 0.f);
            float x1 = fmaxf(v[1] + bbv.y, 0.f);
            float x2 = fmaxf(v[2] + bbv.z, 0.f);
            float x3 = fmaxf(v[3] + bbv.w, 0.f);
            ushort4 o;
            o.x = f2b(x0); o.y = f2b(x1); o.z = f2b(x2); o.w = f2b(x3);
            *(ushort4*)&Ct[(size_t)n * 512 + out_off + mbase] = o;
        }
    }
}

// ---------------------------------------------------------------------------
// Fused layer 3 + layer 4 + slice + transpose + concat (R6 verbatim).
// Grid (128, 2): 64-n-row tile, branch = blockIdx.y. K=256, full M=128 per
// block; layer 4 (7 obj rows) from f32 h3 in LDS (stride 132), f32 out.
// out[0:32768) = rx n*4+k ; out[32768:57344) = tx n*3+k.
// ---------------------------------------------------------------------------
__global__ __launch_bounds__(256) void gemm3_final_k(
    const u16* __restrict__ Ar, const u16* __restrict__ At,
    const float* __restrict__ b3r, const float* __restrict__ b3t,
    const u16* __restrict__ Bt,          // h2t, stride 512
    const float* __restrict__ w4r, const float* __restrict__ b4r,
    const float* __restrict__ w4t, const float* __restrict__ b4t,
    const int* __restrict__ objp, float* __restrict__ out)
{
    __shared__ __align__(16) u16 lds_a[128 * 32];
    __shared__ __align__(16) u16 lds_b[64 * 32];
    __shared__ __align__(16) float lds_h[64 * 132];  // h3 f32, padded stride
    __shared__ __align__(16) float lds_w[4 * 132];   // obj-selected w4 rows

    const int t = threadIdx.x;
    const int n0 = blockIdx.x * 64;
    const int branch = blockIdx.y;

    const u16* A = branch ? At : Ar;
    const float* bias = branch ? b3t : b3r;
    const int b_off = branch * 256;

    const int w = t >> 6, l = t & 63;
    const int sr = l >> 2, sc = (l & 3) * 8;

    const u16* gA0 = A + (size_t)(w * 32 + sr) * 256 + sc;
    const u16* gA1 = gA0 + (size_t)16 * 256;
    u16* lA0 = &lds_a[w * 1024];
    u16* lA1 = lA0 + 512;

    const u16* gB0 = Bt + (size_t)(n0 + w * 16 + sr) * 512 + b_off + sc;
    u16* lB0 = &lds_b[w * 512];

    const int wm = (w & 1) * 64;
    const int wn = (w >> 1) * 32;
    const int lrow = l & 15, quad = l >> 4;
    const u16* fa = &lds_a[(wm + lrow) * 32 + quad * 8];
    const u16* fb = &lds_b[(wn + lrow) * 32 + quad * 8];

    f32x4 acc[4][2];
#pragma unroll
    for (int i = 0; i < 4; ++i)
#pragma unroll
        for (int j = 0; j < 2; ++j)
            acc[i][j] = (f32x4){0.f, 0.f, 0.f, 0.f};

    ld_lds16(gA0, lA0); ld_lds16(gA1, lA1);
    ld_lds16(gB0, lB0);

    for (int kt = 0; kt < 256; kt += 32) {
        __syncthreads();
        bf16x8 af[4], bfr[2];
#pragma unroll
        for (int i = 0; i < 4; ++i) af[i] = *(const bf16x8*)(fa + i * 16 * 32);
#pragma unroll
        for (int j = 0; j < 2; ++j) bfr[j] = *(const bf16x8*)(fb + j * 16 * 32);
        __syncthreads();
        if (kt + 32 < 256) {
            gA0 += 32; gA1 += 32; gB0 += 32;
            ld_lds16(gA0, lA0); ld_lds16(gA1, lA1);
            ld_lds16(gB0, lB0);
        }
#pragma unroll
        for (int i = 0; i < 4; ++i)
#pragma unroll
            for (int j = 0; j < 2; ++j)
                acc[i][j] = __builtin_amdgcn_mfma_f32_16x16x32_bf16(
                    af[i], bfr[j], acc[i][j], 0, 0, 0);
    }

    // ---- h3 (f32, relu) -> LDS ----
#pragma unroll
    for (int i = 0; i < 4; ++i) {
        const int mbase = wm + i * 16 + quad * 4;
        const float4 bbv = *(const float4*)&bias[mbase];
#pragma unroll
        for (int j = 0; j < 2; ++j) {
            const int nl = wn + j * 16 + lrow;
            f32x4 v = acc[i][j];
            float4 x;
            x.x = fmaxf(v[0] + bbv.x, 0.f); x.y = fmaxf(v[1] + bbv.y, 0.f);
            x.z = fmaxf(v[2] + bbv.z, 0.f); x.w = fmaxf(v[3] + bbv.w, 0.f);
            *(float4*)&lds_h[nl * 132 + mbase] = x;
        }
    }
    // ---- obj-selected w4 rows -> LDS ----
    const int o = objp[0];
    const int NR = branch ? 3 : 4;
    const float* w4 = branch ? w4t : w4r;
    if (t < 128) {
        for (int r = 0; r < NR; ++r)
            lds_w[r * 132 + t] = w4[(size_t)(o * NR + r) * 128 + t];
    }
    __syncthreads();

    // ---- layer 4: thread t -> (n_local = t>>2, k = t&3) ----
    const int nl = t >> 2, k = t & 3;
    if (k < NR) {
        const float4* hp = (const float4*)&lds_h[nl * 132];
        const float4* wp4 = (const float4*)&lds_w[k * 132];
        float s = 0.f;
#pragma unroll
        for (int m4 = 0; m4 < 32; ++m4) {
            float4 h = hp[m4], ww = wp4[m4];
            s = fmaf(h.x, ww.x, s); s = fmaf(h.y, ww.y, s);
            s = fmaf(h.z, ww.z, s); s = fmaf(h.w, ww.w, s);
        }
        const int n = n0 + nl;
        if (branch == 0) out[(size_t)n * 4 + k] = s + b4r[o * 4 + k];
        else             out[32768 + (size_t)n * 3 + k] = s + b4t[o * 3 + k];
    }
}

// ---------------------------------------------------------------------------
extern "C" void kernel_launch(void* const* d_in, const int* in_sizes, int n_in,
                              void* d_out, int out_size, void* d_ws, size_t ws_size,
                              hipStream_t stream)
{
    const float* emb1 = (const float*)d_in[0];
    const float* emb2 = (const float*)d_in[1];
    const float* t1   = (const float*)d_in[2];
    const float* t2   = (const float*)d_in[3];
    const int*   obj  = (const int*)d_in[4];
    const float* w1r = (const float*)d_in[5];  const float* b1r = (const float*)d_in[6];
    const float* w2r = (const float*)d_in[7];  const float* b2r = (const float*)d_in[8];
    const float* w3r = (const float*)d_in[9];  const float* b3r = (const float*)d_in[10];
    const float* w4r = (const float*)d_in[11]; const float* b4r = (const float*)d_in[12];
    const float* w1t = (const float*)d_in[13]; const float* b1t = (const float*)d_in[14];
    const float* w2t = (const float*)d_in[15]; const float* b2t = (const float*)d_in[16];
    const float* w3t = (const float*)d_in[17]; const float* b3t = (const float*)d_in[18];
    const float* w4t = (const float*)d_in[19]; const float* b4t = (const float*)d_in[20];

    char* ws = (char*)d_ws;
    u64* part  = (u64*)(ws + (1u << 16));                        // 4 MB (64 x 8192 keys)
    u16* emb1t = (u16*)(ws + (8u << 20));                        // 8 MB  (8192x512)
    u16* emb2t = (u16*)(ws + (16u << 20));                       // 8 MB  (8192x512)
    u16* h1t   = (u16*)(ws + (24u << 20));                       // 20 MB (8192x1280)
    u16* wp    = (u16*)(ws + (44u << 20));                       // 3.25 MB packed weights
    u16* h2t   = emb1t;   // reuse after gemm1

    u16* w1rp = wp;            u16* w1tp = wp + 655360;
    u16* w2rp = wp + 1310720;  u16* w2tp = wp + 1474560;
    u16* w3rp = wp + 1638400;  u16* w3tp = wp + 1671168;

    prep_k<<<PREP_TRANS_END, 256, 0, stream>>>(w1r, w1t, w2r, w2t, w3r, w3t, wp,
                                               t1, t2, part,
                                               emb1, emb2, emb1t, emb2t);
    gemm1_k<<<dim3(64, 5, 2), 256, 0, stream>>>(w1rp, w1tp, b1r, b1t,
                                                emb1t, emb2t, part, h1t);
    gemm2_k<<<dim3(128, 2, 2), 256, 0, stream>>>(w2rp, w2tp, b2r, b2t, h1t, h2t);
    gemm3_final_k<<<dim3(128, 2), 256, 0, stream>>>(w3rp, w3tp, b3r, b3t, h2t,
                                                    w4r, b4r, w4t, b4t, obj, (float*)d_out);
}